// Round 1
// baseline (203.273 us; speedup 1.0000x reference)
//
#include <hip/hip_runtime.h>
#include <math.h>

#define TT 2048
#define HH 512   // hidden = NUM_HEADS*DIM_KEY
#define NH 8
#define DK 64
#define WIN 16
#define NC 33    // 2*WIN+1

// ---------------- projection GEMM: C[M,N] = A[M,K] @ W[N,K]^T + bias[N] ----
// 64x64 tile, 256 threads, 4x4 per thread, fp32.
#define BM 64
#define BN 64
#define BKK 16
#define PAD 4

__global__ __launch_bounds__(256) void proj_kernel(
    const float* __restrict__ A, const float* __restrict__ W,
    const float* __restrict__ bias, float* __restrict__ C,
    int M, int N, int K)
{
  __shared__ float As[BKK][BM + PAD];
  __shared__ float Bs[BKK][BN + PAD];
  const int m0 = blockIdx.x * BM;
  const int n0 = blockIdx.y * BN;
  const int t  = threadIdx.x;
  const int tx = t & 15;   // n sub-tile
  const int ty = t >> 4;   // m sub-tile
  const int lrow = t >> 2;        // 0..63 row being staged
  const int lk4  = (t & 3) * 4;   // k quad being staged

  float acc[4][4] = {};

  for (int k0 = 0; k0 < K; k0 += BKK) {
    float4 av = *(const float4*)(A + (size_t)(m0 + lrow) * K + k0 + lk4);
    float4 wv = *(const float4*)(W + (size_t)(n0 + lrow) * K + k0 + lk4);
    As[lk4+0][lrow] = av.x; As[lk4+1][lrow] = av.y;
    As[lk4+2][lrow] = av.z; As[lk4+3][lrow] = av.w;
    Bs[lk4+0][lrow] = wv.x; Bs[lk4+1][lrow] = wv.y;
    Bs[lk4+2][lrow] = wv.z; Bs[lk4+3][lrow] = wv.w;
    __syncthreads();
#pragma unroll
    for (int kk = 0; kk < BKK; ++kk) {
      float ra[4], rb[4];
#pragma unroll
      for (int i = 0; i < 4; ++i) ra[i] = As[kk][ty*4 + i];
#pragma unroll
      for (int j = 0; j < 4; ++j) rb[j] = Bs[kk][tx*4 + j];
#pragma unroll
      for (int i = 0; i < 4; ++i)
#pragma unroll
        for (int j = 0; j < 4; ++j)
          acc[i][j] = fmaf(ra[i], rb[j], acc[i][j]);
    }
    __syncthreads();
  }

#pragma unroll
  for (int i = 0; i < 4; ++i) {
    const int m = m0 + ty*4 + i;
#pragma unroll
    for (int j = 0; j < 4; ++j) {
      const int n = n0 + tx*4 + j;
      C[(size_t)m * N + n] = acc[i][j] + bias[n];
    }
  }
}

// ---------------- windowed attention + softmax + gather --------------------
// grid: B*T blocks, 512 threads (8 waves = 8 heads). Wave h, lane c:
//   j = clip(i-16, 0, T-33) + c ; score valid iff |j - i| <= 16 and c < 33.
__global__ __launch_bounds__(512) void attn_kernel(
    const float* __restrict__ Q, const float* __restrict__ Kp,
    float* __restrict__ out)
{
  const int row = blockIdx.x;          // b*T + i
  const int b = row >> 11;             // T = 2048
  const int i = row & (TT - 1);
  const int h = threadIdx.x >> 6;
  const int c = threadIdx.x & 63;

  __shared__ float qs[HH];
  qs[threadIdx.x] = Q[(size_t)row * HH + threadIdx.x];
  __syncthreads();

  int start = i - WIN;
  if (start < 0) start = 0;
  if (start > TT - NC) start = TT - NC;

  float score = -INFINITY;
  if (c < NC) {
    const int j = start + c;
    if (j >= i - WIN && j <= i + WIN) {
      const float* krow = Kp + ((size_t)b * TT + j) * HH + h * DK;
      const float* qrow = qs + h * DK;
      float acc = 0.f;
#pragma unroll
      for (int d = 0; d < DK; d += 4) {
        float4 kv = *(const float4*)(krow + d);
        acc = fmaf(qrow[d+0], kv.x, acc);
        acc = fmaf(qrow[d+1], kv.y, acc);
        acc = fmaf(qrow[d+2], kv.z, acc);
        acc = fmaf(qrow[d+3], kv.w, acc);
      }
      score = acc * 0.125f;   // 1/TEMP = 1/sqrt(64)
    }
  }

  // wave-wide softmax (invalid lanes hold -inf -> contribute 0)
  float mx = score;
#pragma unroll
  for (int off = 32; off; off >>= 1) mx = fmaxf(mx, __shfl_xor(mx, off));
  const float e = (score == -INFINITY) ? 0.f : __expf(score - mx);
  float sum = e;
#pragma unroll
  for (int off = 32; off; off >>= 1) sum += __shfl_xor(sum, off);

  if (c < NC)
    out[(((size_t)b * NH + h) * TT + i) * NC + c] = e / sum;
}

extern "C" void kernel_launch(void* const* d_in, const int* in_sizes, int n_in,
                              void* d_out, int out_size, void* d_ws, size_t ws_size,
                              hipStream_t stream)
{
  const float* query = (const float*)d_in[0];
  const float* key   = (const float*)d_in[1];
  const float* Wq    = (const float*)d_in[2];
  const float* bq    = (const float*)d_in[3];
  const float* Wk    = (const float*)d_in[4];
  const float* bk    = (const float*)d_in[5];
  float* out = (float*)d_out;

  const int B = 4, M = B * TT;      // 8192 rows
  float* Qp = (float*)d_ws;                 // [M, 512]
  float* Kp = Qp + (size_t)M * HH;          // [M, 512]

  dim3 gg(M / BM, HH / BN);
  proj_kernel<<<gg, 256, 0, stream>>>(query, Wq, bq, Qp, M, HH, HH);
  proj_kernel<<<gg, 256, 0, stream>>>(key,   Wk, bk, Kp, M, HH, HH);
  attn_kernel<<<dim3(M), 512, 0, stream>>>(Qp, Kp, out);
}

// Round 2
// 159.202 us; speedup vs baseline: 1.2768x; 1.2768x over previous
//
#include <hip/hip_runtime.h>
#include <math.h>

#define TT 2048
#define HH 512   // hidden = NUM_HEADS*DIM_KEY
#define NH 8
#define DK 64
#define WIN 16
#define NC 33    // 2*WIN+1

// ---------------- projection GEMM: C[M,N] = A[M,K] @ W[N,K]^T + bias[N] ----
// 64x64 tile, 256 threads, 4x4 per thread, fp32.
#define BM 64
#define BN 64
#define BKK 16
#define PAD 4

__global__ __launch_bounds__(256) void proj_kernel(
    const float* __restrict__ A, const float* __restrict__ W,
    const float* __restrict__ bias, float* __restrict__ C,
    int M, int N, int K)
{
  __shared__ float As[BKK][BM + PAD];
  __shared__ float Bs[BKK][BN + PAD];
  const int m0 = blockIdx.x * BM;
  const int n0 = blockIdx.y * BN;
  const int t  = threadIdx.x;
  const int tx = t & 15;   // n sub-tile
  const int ty = t >> 4;   // m sub-tile
  const int lrow = t >> 2;        // 0..63 row being staged
  const int lk4  = (t & 3) * 4;   // k quad being staged

  float acc[4][4] = {};

  for (int k0 = 0; k0 < K; k0 += BKK) {
    float4 av = *(const float4*)(A + (size_t)(m0 + lrow) * K + k0 + lk4);
    float4 wv = *(const float4*)(W + (size_t)(n0 + lrow) * K + k0 + lk4);
    As[lk4+0][lrow] = av.x; As[lk4+1][lrow] = av.y;
    As[lk4+2][lrow] = av.z; As[lk4+3][lrow] = av.w;
    Bs[lk4+0][lrow] = wv.x; Bs[lk4+1][lrow] = wv.y;
    Bs[lk4+2][lrow] = wv.z; Bs[lk4+3][lrow] = wv.w;
    __syncthreads();
#pragma unroll
    for (int kk = 0; kk < BKK; ++kk) {
      float ra[4], rb[4];
#pragma unroll
      for (int i = 0; i < 4; ++i) ra[i] = As[kk][ty*4 + i];
#pragma unroll
      for (int j = 0; j < 4; ++j) rb[j] = Bs[kk][tx*4 + j];
#pragma unroll
      for (int i = 0; i < 4; ++i)
#pragma unroll
        for (int j = 0; j < 4; ++j)
          acc[i][j] = fmaf(ra[i], rb[j], acc[i][j]);
    }
    __syncthreads();
  }

#pragma unroll
  for (int i = 0; i < 4; ++i) {
    const int m = m0 + ty*4 + i;
#pragma unroll
    for (int j = 0; j < 4; ++j) {
      const int n = n0 + tx*4 + j;
      C[(size_t)m * N + n] = acc[i][j] + bias[n];
    }
  }
}

// ---------------- windowed attention + softmax + gather --------------------
// Tiled: block = (64-row tile, head). Stage Q[64][64] + K[96][64] in LDS
// (stride 68 floats: 16B-aligned rows, breaks the 32-way column conflict).
// 8 waves x 8 rows each; lane c = window column c.
#define RT 64    // rows per tile
#define KT 96    // K rows staged (covers [r0-16, r0+79])
#define KS 68    // padded LDS row stride (floats)

__global__ __launch_bounds__(512) void attn_kernel(
    const float* __restrict__ Q, const float* __restrict__ Kp,
    float* __restrict__ out)
{
  __shared__ float Qs[RT][KS];
  __shared__ float Ks[KT][KS];

  const int tile = blockIdx.x;          // 0..127 : b*32 + rowtile
  const int h = blockIdx.y;
  const int b = tile >> 5;              // 32 tiles per batch (T/RT)
  const int r0 = (tile & 31) * RT;
  const int tid = threadIdx.x;

  int jbase = r0 - WIN;
  if (jbase < 0) jbase = 0;

  // ---- stage Q (1024 quads) and K (1536 quads), 512 threads ----
#pragma unroll
  for (int p = 0; p < 2; ++p) {
    const int u = tid + p * 512;
    const int r = u >> 4, d4 = u & 15;
    float4 v = *(const float4*)(Q + ((size_t)(b * TT + r0 + r)) * HH + h * DK + d4 * 4);
    *(float4*)&Qs[r][d4 * 4] = v;
  }
#pragma unroll
  for (int p = 0; p < 3; ++p) {
    const int u = tid + p * 512;
    const int r = u >> 4, d4 = u & 15;
    int j = jbase + r;
    if (j > TT - 1) j = TT - 1;         // clamp (rows past T are never used)
    float4 v = *(const float4*)(Kp + ((size_t)(b * TT + j)) * HH + h * DK + d4 * 4);
    *(float4*)&Ks[r][d4 * 4] = v;
  }
  __syncthreads();

  const int w = tid >> 6;   // wave 0..7
  const int c = tid & 63;   // lane = window column

#pragma unroll
  for (int rr = 0; rr < 8; ++rr) {
    const int r = w * 8 + rr;
    const int i = r0 + r;
    int start = i - WIN;
    if (start < 0) start = 0;
    if (start > TT - NC) start = TT - NC;
    const int s0 = start - jbase;

    const int j = start + c;
    const bool valid = (c < NC) && (j >= i - WIN) && (j <= i + WIN);
    int kr = s0 + c;
    if (kr > KT - 1) kr = KT - 1;       // clamp OOB lanes (result discarded)

    float4 acc4 = {0.f, 0.f, 0.f, 0.f};
#pragma unroll
    for (int d4 = 0; d4 < 16; ++d4) {
      float4 qv = *(const float4*)&Qs[r][d4 * 4];   // wave-broadcast
      float4 kv = *(const float4*)&Ks[kr][d4 * 4];
      acc4.x = fmaf(qv.x, kv.x, acc4.x);
      acc4.y = fmaf(qv.y, kv.y, acc4.y);
      acc4.z = fmaf(qv.z, kv.z, acc4.z);
      acc4.w = fmaf(qv.w, kv.w, acc4.w);
    }
    const float dot = (acc4.x + acc4.y) + (acc4.z + acc4.w);
    const float score = valid ? dot * 0.125f : -INFINITY;

    float mx = score;
#pragma unroll
    for (int off = 32; off; off >>= 1) mx = fmaxf(mx, __shfl_xor(mx, off));
    const float e = valid ? __expf(score - mx) : 0.f;
    float sum = e;
#pragma unroll
    for (int off = 32; off; off >>= 1) sum += __shfl_xor(sum, off);

    if (c < NC)
      out[(((size_t)b * NH + h) * TT + i) * NC + c] = e / sum;
  }
}

extern "C" void kernel_launch(void* const* d_in, const int* in_sizes, int n_in,
                              void* d_out, int out_size, void* d_ws, size_t ws_size,
                              hipStream_t stream)
{
  const float* query = (const float*)d_in[0];
  const float* key   = (const float*)d_in[1];
  const float* Wq    = (const float*)d_in[2];
  const float* bq    = (const float*)d_in[3];
  const float* Wk    = (const float*)d_in[4];
  const float* bk    = (const float*)d_in[5];
  float* out = (float*)d_out;

  const int B = 4, M = B * TT;      // 8192 rows
  float* Qp = (float*)d_ws;                 // [M, 512]
  float* Kp = Qp + (size_t)M * HH;          // [M, 512]

  dim3 gg(M / BM, HH / BN);
  proj_kernel<<<gg, 256, 0, stream>>>(query, Wq, bq, Qp, M, HH, HH);
  proj_kernel<<<gg, 256, 0, stream>>>(key,   Wk, bk, Kp, M, HH, HH);
  attn_kernel<<<dim3(M / RT, NH), 512, 0, stream>>>(Qp, Kp, out);
}

// Round 3
// 83.088 us; speedup vs baseline: 2.4465x; 1.9161x over previous
//
#include <hip/hip_runtime.h>
#include <math.h>

#define TT 2048
#define HH 512   // hidden = NUM_HEADS*DIM_KEY
#define NH 8
#define DK 64
#define WIN 16
#define NC 33    // 2*WIN+1

typedef __attribute__((ext_vector_type(8))) short bf16x8;
typedef __attribute__((ext_vector_type(4))) float f32x4;

__device__ inline ushort f2bf(float f) {   // RNE float -> bf16 bits
  uint u = __builtin_bit_cast(uint, f);
  return (ushort)((u + 0x7FFFu + ((u >> 16) & 1u)) >> 16);
}

// ---------------- projection GEMM (bf16 MFMA): C = A[M,K] @ W[N,K]^T + b ---
// M=8192 N=512 K=512. BM=64 BN=128 BK=64, 256 threads = 4 waves (2x2),
// wave tile 32x64 = 2x4 fragments of 16x16x32. fp32->bf16 RNE in staging.
#define PBM 64
#define PBN 128
#define PBK 64
#define LDSK 72   // padded LDS row stride in ushorts (144 B)

__global__ __launch_bounds__(256) void proj_mfma(
    const float* __restrict__ A, const float* __restrict__ W,
    const float* __restrict__ bias, float* __restrict__ C)
{
  __shared__ ushort As[PBM][LDSK];
  __shared__ ushort Ws[PBN][LDSK];

  const int m0 = blockIdx.x * PBM;
  const int n0 = blockIdx.y * PBN;
  const int t  = threadIdx.x;
  const int l  = t & 63;
  const int w  = t >> 6;
  const int wr = (w >> 1) * 32;   // wave row offset in tile
  const int wc = (w & 1) * 64;    // wave col offset in tile
  const int lr = l & 15;          // fragment row/col lane index
  const int lk = (l >> 4) * 8;    // fragment k slice

  f32x4 acc[2][4] = {};

  for (int k0 = 0; k0 < HH; k0 += PBK) {
    // ---- stage A: 64x64 elems, 512 8-elem tasks, 2/thread ----
#pragma unroll
    for (int p = 0; p < 2; ++p) {
      const int u = t + p * 256;
      const int r = u >> 3, kc = u & 7;
      const float4* g = (const float4*)(A + (size_t)(m0 + r) * HH + k0 + kc * 8);
      float4 x = g[0], y = g[1];
      union { ushort u16[8]; uint4 v; } pk;
      pk.u16[0]=f2bf(x.x); pk.u16[1]=f2bf(x.y); pk.u16[2]=f2bf(x.z); pk.u16[3]=f2bf(x.w);
      pk.u16[4]=f2bf(y.x); pk.u16[5]=f2bf(y.y); pk.u16[6]=f2bf(y.z); pk.u16[7]=f2bf(y.w);
      *(uint4*)&As[r][kc * 8] = pk.v;
    }
    // ---- stage W: 128x64 elems, 1024 tasks, 4/thread ----
#pragma unroll
    for (int p = 0; p < 4; ++p) {
      const int u = t + p * 256;
      const int r = u >> 3, kc = u & 7;
      const float4* g = (const float4*)(W + (size_t)(n0 + r) * HH + k0 + kc * 8);
      float4 x = g[0], y = g[1];
      union { ushort u16[8]; uint4 v; } pk;
      pk.u16[0]=f2bf(x.x); pk.u16[1]=f2bf(x.y); pk.u16[2]=f2bf(x.z); pk.u16[3]=f2bf(x.w);
      pk.u16[4]=f2bf(y.x); pk.u16[5]=f2bf(y.y); pk.u16[6]=f2bf(y.z); pk.u16[7]=f2bf(y.w);
      *(uint4*)&Ws[r][kc * 8] = pk.v;
    }
    __syncthreads();

#pragma unroll
    for (int kk = 0; kk < PBK; kk += 32) {
      bf16x8 af[2], bf[4];
#pragma unroll
      for (int m = 0; m < 2; ++m)
        af[m] = *(const bf16x8*)&As[wr + m * 16 + lr][kk + lk];
#pragma unroll
      for (int n = 0; n < 4; ++n)
        bf[n] = *(const bf16x8*)&Ws[wc + n * 16 + lr][kk + lk];
#pragma unroll
      for (int m = 0; m < 2; ++m)
#pragma unroll
        for (int n = 0; n < 4; ++n)
          acc[m][n] = __builtin_amdgcn_mfma_f32_16x16x32_bf16(af[m], bf[n], acc[m][n], 0, 0, 0);
    }
    __syncthreads();
  }

  // ---- epilogue: D row=(l>>4)*4+q, col=l&15 (m89-verified) ----
#pragma unroll
  for (int n = 0; n < 4; ++n) {
    const int col = n0 + wc + n * 16 + lr;
    const float bc = bias[col];
#pragma unroll
    for (int m = 0; m < 2; ++m) {
      const int rbase = m0 + wr + m * 16 + (l >> 4) * 4;
#pragma unroll
      for (int q = 0; q < 4; ++q)
        C[(size_t)(rbase + q) * HH + col] = acc[m][n][q] + bc;
    }
  }
}

// ---------------- windowed attention + softmax + gather --------------------
#define RT 64    // rows per tile
#define KT 96    // K rows staged
#define KS 68    // padded LDS row stride (floats)

__global__ __launch_bounds__(512) void attn_kernel(
    const float* __restrict__ Q, const float* __restrict__ Kp,
    float* __restrict__ out)
{
  __shared__ float Qs[RT][KS];
  __shared__ float Ks[KT][KS];

  const int tile = blockIdx.x;
  const int h = blockIdx.y;
  const int b = tile >> 5;
  const int r0 = (tile & 31) * RT;
  const int tid = threadIdx.x;

  int jbase = r0 - WIN;
  if (jbase < 0) jbase = 0;

#pragma unroll
  for (int p = 0; p < 2; ++p) {
    const int u = tid + p * 512;
    const int r = u >> 4, d4 = u & 15;
    float4 v = *(const float4*)(Q + ((size_t)(b * TT + r0 + r)) * HH + h * DK + d4 * 4);
    *(float4*)&Qs[r][d4 * 4] = v;
  }
#pragma unroll
  for (int p = 0; p < 3; ++p) {
    const int u = tid + p * 512;
    const int r = u >> 4, d4 = u & 15;
    int j = jbase + r;
    if (j > TT - 1) j = TT - 1;
    float4 v = *(const float4*)(Kp + ((size_t)(b * TT + j)) * HH + h * DK + d4 * 4);
    *(float4*)&Ks[r][d4 * 4] = v;
  }
  __syncthreads();

  const int w = tid >> 6;
  const int c = tid & 63;

#pragma unroll
  for (int rr = 0; rr < 8; ++rr) {
    const int r = w * 8 + rr;
    const int i = r0 + r;
    int start = i - WIN;
    if (start < 0) start = 0;
    if (start > TT - NC) start = TT - NC;
    const int s0 = start - jbase;

    const int j = start + c;
    const bool valid = (c < NC) && (j >= i - WIN) && (j <= i + WIN);
    int kr = s0 + c;
    if (kr > KT - 1) kr = KT - 1;

    float4 acc4 = {0.f, 0.f, 0.f, 0.f};
#pragma unroll
    for (int d4 = 0; d4 < 16; ++d4) {
      float4 qv = *(const float4*)&Qs[r][d4 * 4];
      float4 kv = *(const float4*)&Ks[kr][d4 * 4];
      acc4.x = fmaf(qv.x, kv.x, acc4.x);
      acc4.y = fmaf(qv.y, kv.y, acc4.y);
      acc4.z = fmaf(qv.z, kv.z, acc4.z);
      acc4.w = fmaf(qv.w, kv.w, acc4.w);
    }
    const float dot = (acc4.x + acc4.y) + (acc4.z + acc4.w);
    const float score = valid ? dot * 0.125f : -INFINITY;

    float mx = score;
#pragma unroll
    for (int off = 32; off; off >>= 1) mx = fmaxf(mx, __shfl_xor(mx, off));
    const float e = valid ? __expf(score - mx) : 0.f;
    float sum = e;
#pragma unroll
    for (int off = 32; off; off >>= 1) sum += __shfl_xor(sum, off);

    if (c < NC)
      out[(((size_t)b * NH + h) * TT + i) * NC + c] = e / sum;
  }
}

extern "C" void kernel_launch(void* const* d_in, const int* in_sizes, int n_in,
                              void* d_out, int out_size, void* d_ws, size_t ws_size,
                              hipStream_t stream)
{
  const float* query = (const float*)d_in[0];
  const float* key   = (const float*)d_in[1];
  const float* Wq    = (const float*)d_in[2];
  const float* bq    = (const float*)d_in[3];
  const float* Wk    = (const float*)d_in[4];
  const float* bk    = (const float*)d_in[5];
  float* out = (float*)d_out;

  const int B = 4, M = B * TT;      // 8192 rows
  float* Qp = (float*)d_ws;                 // [M, 512]
  float* Kp = Qp + (size_t)M * HH;          // [M, 512]

  dim3 gg(M / PBM, HH / PBN);               // 128 x 4 = 512 blocks
  proj_mfma<<<gg, 256, 0, stream>>>(query, Wq, bq, Qp);
  proj_mfma<<<gg, 256, 0, stream>>>(key,   Wk, bk, Kp);
  attn_kernel<<<dim3(M / RT, NH), 512, 0, stream>>>(Qp, Kp, out);
}

// Round 4
// 57.091 us; speedup vs baseline: 3.5605x; 1.4554x over previous
//
#include <hip/hip_runtime.h>
#include <hip/hip_bf16.h>
#include <math.h>

#define TT 2048
#define HH 512   // hidden = NUM_HEADS*DIM_KEY
#define NH 8
#define DK 64
#define WIN 16
#define NC 33    // 2*WIN+1

typedef __attribute__((ext_vector_type(8))) short bf16x8;
typedef __attribute__((ext_vector_type(4))) float f32x4;

__device__ inline float bf2f(ushort u) {
  return __builtin_bit_cast(float, (uint)u << 16);
}
__device__ inline ushort f2bf(float f) {   // RNE float -> bf16 bits
  uint u = __builtin_bit_cast(uint, f);
  return (ushort)((u + 0x7FFFu + ((u >> 16) & 1u)) >> 16);
}
__device__ inline ushort cvt1(float f) {   // compiler cast (hits v_cvt_pk)
  __hip_bfloat16 h = __float2bfloat16(f);
  return __builtin_bit_cast(ushort, h);
}

// ---------------- W fp32 -> bf16 pre-convert (both weights) ---------------
__global__ __launch_bounds__(256) void cvt_w(
    const float* __restrict__ Wq, const float* __restrict__ Wk,
    ushort* __restrict__ Wqb, ushort* __restrict__ Wkb)
{
  const int id = blockIdx.x * 256 + threadIdx.x;   // 65536 tasks x 8 elems
  const float* src = (id < 32768) ? Wq : Wk;
  ushort* dst = (id < 32768) ? Wqb : Wkb;
  const int off = (id & 32767) * 8;
  float4 x = *(const float4*)(src + off);
  float4 y = *(const float4*)(src + off + 4);
  union { ushort s[8]; uint4 v; } pk;
  pk.s[0]=cvt1(x.x); pk.s[1]=cvt1(x.y); pk.s[2]=cvt1(x.z); pk.s[3]=cvt1(x.w);
  pk.s[4]=cvt1(y.x); pk.s[5]=cvt1(y.y); pk.s[6]=cvt1(y.z); pk.s[7]=cvt1(y.w);
  *(uint4*)(dst + off) = pk.v;
}

// ---------------- projection GEMM (bf16 MFMA): C = A @ W^T + b, bf16 out --
// BM=128 BN=128 BK=64, 256 threads = 4 waves (2x2), wave tile 64x64.
// W staged via global_load_lds (bf16 pre-converted); A reg-staged fp32->bf16.
// gridDim.z selects (query,Wq,bq,Qp) vs (key,Wk,bk,Kp).
#define PBM 128
#define PBN 128
#define PBK 64

__global__ __launch_bounds__(256) void proj_mfma(
    const float* __restrict__ Aq, const float* __restrict__ Ak,
    const ushort* __restrict__ Wqb, const ushort* __restrict__ Wkb,
    const float* __restrict__ bq, const float* __restrict__ bk,
    ushort* __restrict__ Qp, ushort* __restrict__ Kp)
{
  __shared__ ushort As[PBM * PBK];
  __shared__ ushort Ws[PBN * PBK];

  const int z = blockIdx.z;
  const float*  A    = z ? Ak  : Aq;
  const ushort* Wb   = z ? Wkb : Wqb;
  const float*  bias = z ? bk  : bq;
  ushort*       C    = z ? Kp  : Qp;

  const int m0 = blockIdx.x * PBM;
  const int n0 = blockIdx.y * PBN;
  const int t  = threadIdx.x;
  const int l  = t & 63;
  const int w  = t >> 6;
  const int wr = (w >> 1) * 64;   // wave row offset
  const int wc = (w & 1) * 64;    // wave col offset
  const int lr = l & 15;
  const int lk8 = (l >> 4) * 8;

  f32x4 acc[4][4] = {};

  for (int k0 = 0; k0 < HH; k0 += PBK) {
    // ---- W: 4 rounds of global_load_lds (16 B/lane, linear LDS) ----
#pragma unroll
    for (int p = 0; p < 4; ++p) {
      const int u = p * 256 + t;            // 0..1023
      const int r = u >> 3, c8 = u & 7;
      const ushort* gsrc = Wb + (size_t)(n0 + r) * HH + k0 + c8 * 8;
      __builtin_amdgcn_global_load_lds(
          (const __attribute__((address_space(1))) uint*)gsrc,
          (__attribute__((address_space(3))) uint*)(Ws + p * 2048 + w * 512),
          16, 0, 0);
    }
    // ---- A: reg-stage fp32 -> bf16 (compiler cvt) ----
#pragma unroll
    for (int p = 0; p < 4; ++p) {
      const int u = p * 256 + t;
      const int r = u >> 3, c8 = u & 7;
      const float* g = A + (size_t)(m0 + r) * HH + k0 + c8 * 8;
      float4 x = ((const float4*)g)[0], y = ((const float4*)g)[1];
      union { ushort s[8]; uint4 v; } pk;
      pk.s[0]=cvt1(x.x); pk.s[1]=cvt1(x.y); pk.s[2]=cvt1(x.z); pk.s[3]=cvt1(x.w);
      pk.s[4]=cvt1(y.x); pk.s[5]=cvt1(y.y); pk.s[6]=cvt1(y.z); pk.s[7]=cvt1(y.w);
      *(uint4*)&As[u * 8] = pk.v;
    }
    __syncthreads();

#pragma unroll
    for (int kk = 0; kk < PBK; kk += 32) {
      bf16x8 af[4], bf[4];
#pragma unroll
      for (int m = 0; m < 4; ++m)
        af[m] = *(const bf16x8*)&As[(wr + m * 16 + lr) * PBK + kk + lk8];
#pragma unroll
      for (int n = 0; n < 4; ++n)
        bf[n] = *(const bf16x8*)&Ws[(wc + n * 16 + lr) * PBK + kk + lk8];
#pragma unroll
      for (int m = 0; m < 4; ++m)
#pragma unroll
        for (int n = 0; n < 4; ++n)
          acc[m][n] = __builtin_amdgcn_mfma_f32_16x16x32_bf16(af[m], bf[n], acc[m][n], 0, 0, 0);
    }
    __syncthreads();
  }

  // ---- epilogue: D row=(l>>4)*4+q, col=l&15 (round-3 verified) ----
#pragma unroll
  for (int n = 0; n < 4; ++n) {
    const int col = n0 + wc + n * 16 + lr;
    const float bc = bias[col];
#pragma unroll
    for (int m = 0; m < 4; ++m) {
      const int rbase = m0 + wr + m * 16 + (l >> 4) * 4;
#pragma unroll
      for (int q = 0; q < 4; ++q)
        C[(size_t)(rbase + q) * HH + col] = f2bf(acc[m][n][q] + bc);
    }
  }
}

// ---------------- windowed attention + softmax + gather (bf16 in) ---------
#define RT 64    // rows per tile
#define KT 96    // K rows staged
#define KS 68    // padded LDS row stride (floats)

__global__ __launch_bounds__(512) void attn_kernel(
    const ushort* __restrict__ Q, const ushort* __restrict__ Kp,
    float* __restrict__ out)
{
  __shared__ float Qs[RT][KS];
  __shared__ float Ks[KT][KS];

  const int tile = blockIdx.x;
  const int h = blockIdx.y;
  const int b = tile >> 5;
  const int r0 = (tile & 31) * RT;
  const int tid = threadIdx.x;

  int jbase = r0 - WIN;
  if (jbase < 0) jbase = 0;

  // ---- stage Q: 512 chunks of 8 bf16, exactly 1/thread ----
  {
    const int r = tid >> 3, c8 = tid & 7;
    union { uint4 v; ushort s[8]; } pk;
    pk.v = *(const uint4*)(Q + ((size_t)(b * TT + r0 + r)) * HH + h * DK + c8 * 8);
    float4 lo = { bf2f(pk.s[0]), bf2f(pk.s[1]), bf2f(pk.s[2]), bf2f(pk.s[3]) };
    float4 hi = { bf2f(pk.s[4]), bf2f(pk.s[5]), bf2f(pk.s[6]), bf2f(pk.s[7]) };
    *(float4*)&Qs[r][c8 * 8] = lo;
    *(float4*)&Qs[r][c8 * 8 + 4] = hi;
  }
  // ---- stage K: 768 chunks ----
#pragma unroll
  for (int p = 0; p < 2; ++p) {
    const int u = tid + p * 512;
    if (u < KT * 8) {
      const int r = u >> 3, c8 = u & 7;
      int j = jbase + r;
      if (j > TT - 1) j = TT - 1;
      union { uint4 v; ushort s[8]; } pk;
      pk.v = *(const uint4*)(Kp + ((size_t)(b * TT + j)) * HH + h * DK + c8 * 8);
      float4 lo = { bf2f(pk.s[0]), bf2f(pk.s[1]), bf2f(pk.s[2]), bf2f(pk.s[3]) };
      float4 hi = { bf2f(pk.s[4]), bf2f(pk.s[5]), bf2f(pk.s[6]), bf2f(pk.s[7]) };
      *(float4*)&Ks[r][c8 * 8] = lo;
      *(float4*)&Ks[r][c8 * 8 + 4] = hi;
    }
  }
  __syncthreads();

  const int w = tid >> 6;
  const int c = tid & 63;

#pragma unroll
  for (int rr = 0; rr < 8; ++rr) {
    const int r = w * 8 + rr;
    const int i = r0 + r;
    int start = i - WIN;
    if (start < 0) start = 0;
    if (start > TT - NC) start = TT - NC;
    const int s0 = start - jbase;

    const int j = start + c;
    const bool valid = (c < NC) && (j >= i - WIN) && (j <= i + WIN);
    int kr = s0 + c;
    if (kr > KT - 1) kr = KT - 1;

    float4 acc4 = {0.f, 0.f, 0.f, 0.f};
#pragma unroll
    for (int d4 = 0; d4 < 16; ++d4) {
      float4 qv = *(const float4*)&Qs[r][d4 * 4];
      float4 kv = *(const float4*)&Ks[kr][d4 * 4];
      acc4.x = fmaf(qv.x, kv.x, acc4.x);
      acc4.y = fmaf(qv.y, kv.y, acc4.y);
      acc4.z = fmaf(qv.z, kv.z, acc4.z);
      acc4.w = fmaf(qv.w, kv.w, acc4.w);
    }
    const float dot = (acc4.x + acc4.y) + (acc4.z + acc4.w);
    const float score = valid ? dot * 0.125f : -INFINITY;

    float mx = score;
#pragma unroll
    for (int off = 32; off; off >>= 1) mx = fmaxf(mx, __shfl_xor(mx, off));
    const float e = valid ? __expf(score - mx) : 0.f;
    float sum = e;
#pragma unroll
    for (int off = 32; off; off >>= 1) sum += __shfl_xor(sum, off);

    if (c < NC)
      out[(((size_t)b * NH + h) * TT + i) * NC + c] = e / sum;
  }
}

extern "C" void kernel_launch(void* const* d_in, const int* in_sizes, int n_in,
                              void* d_out, int out_size, void* d_ws, size_t ws_size,
                              hipStream_t stream)
{
  const float* query = (const float*)d_in[0];
  const float* key   = (const float*)d_in[1];
  const float* Wq    = (const float*)d_in[2];
  const float* bq    = (const float*)d_in[3];
  const float* Wk    = (const float*)d_in[4];
  const float* bk    = (const float*)d_in[5];
  float* out = (float*)d_out;

  const int B = 4, M = B * TT;      // 8192 rows
  ushort* Wqb = (ushort*)d_ws;                  // 512x512 bf16
  ushort* Wkb = Wqb + (size_t)HH * HH;
  ushort* Qp  = Wkb + (size_t)HH * HH;          // [M, 512] bf16
  ushort* Kp  = Qp + (size_t)M * HH;

  cvt_w<<<256, 256, 0, stream>>>(Wq, Wk, Wqb, Wkb);
  proj_mfma<<<dim3(M / PBM, HH / PBN, 2), 256, 0, stream>>>(
      query, key, Wqb, Wkb, bq, bk, Qp, Kp);
  attn_kernel<<<dim3(M / RT, NH), 512, 0, stream>>>(Qp, Kp, out);
}

// Round 5
// 37.250 us; speedup vs baseline: 5.4570x; 1.5326x over previous
//
#include <hip/hip_runtime.h>
#include <hip/hip_bf16.h>
#include <math.h>

#define TT 2048
#define HH 512   // hidden = NUM_HEADS*DIM_KEY
#define NH 8
#define DK 64
#define WIN 16
#define NC 33    // 2*WIN+1

typedef __attribute__((ext_vector_type(8))) short bf16x8;
typedef __attribute__((ext_vector_type(4))) float f32x4;

__device__ inline ushort f2bf(float f) {   // RNE float -> bf16 bits
  uint u = __builtin_bit_cast(uint, f);
  return (ushort)((u + 0x7FFFu + ((u >> 16) & 1u)) >> 16);
}
__device__ inline ushort cvt1(float f) {   // compiler cast (v_cvt_pk capable)
  __hip_bfloat16 h = __float2bfloat16(f);
  return __builtin_bit_cast(ushort, h);
}

// ---------------- W fp32 -> bf16 pre-convert (both weights) ---------------
__global__ __launch_bounds__(256) void cvt_w(
    const float* __restrict__ Wq, const float* __restrict__ Wk,
    ushort* __restrict__ Wqb, ushort* __restrict__ Wkb)
{
  const int id = blockIdx.x * 256 + threadIdx.x;   // 65536 tasks x 8 elems
  const float* src = (id < 32768) ? Wq : Wk;
  ushort* dst = (id < 32768) ? Wqb : Wkb;
  const int off = (id & 32767) * 8;
  float4 x = *(const float4*)(src + off);
  float4 y = *(const float4*)(src + off + 4);
  union { ushort s[8]; uint4 v; } pk;
  pk.s[0]=cvt1(x.x); pk.s[1]=cvt1(x.y); pk.s[2]=cvt1(x.z); pk.s[3]=cvt1(x.w);
  pk.s[4]=cvt1(y.x); pk.s[5]=cvt1(y.y); pk.s[6]=cvt1(y.z); pk.s[7]=cvt1(y.w);
  *(uint4*)(dst + off) = pk.v;
}

// ---------------- projection GEMM (bf16 MFMA): C = A @ W^T + b, bf16 out --
// BM=128 BN=128 BK=64, 256 threads = 4 waves (2x2), wave tile 64x64.
// W staged via global_load_lds (bf16 pre-converted); A reg-staged fp32->bf16.
// gridDim.z selects (query,Wq,bq,Qp) vs (key,Wk,bk,Kp).
#define PBM 128
#define PBN 128
#define PBK 64

__global__ __launch_bounds__(256) void proj_mfma(
    const float* __restrict__ Aq, const float* __restrict__ Ak,
    const ushort* __restrict__ Wqb, const ushort* __restrict__ Wkb,
    const float* __restrict__ bq, const float* __restrict__ bk,
    ushort* __restrict__ Qp, ushort* __restrict__ Kp)
{
  __shared__ ushort As[PBM * PBK];
  __shared__ ushort Ws[PBN * PBK];

  const int z = blockIdx.z;
  const float*  A    = z ? Ak  : Aq;
  const ushort* Wb   = z ? Wkb : Wqb;
  const float*  bias = z ? bk  : bq;
  ushort*       C    = z ? Kp  : Qp;

  const int m0 = blockIdx.x * PBM;
  const int n0 = blockIdx.y * PBN;
  const int t  = threadIdx.x;
  const int l  = t & 63;
  const int w  = t >> 6;
  const int wr = (w >> 1) * 64;   // wave row offset
  const int wc = (w & 1) * 64;    // wave col offset
  const int lr = l & 15;
  const int lk8 = (l >> 4) * 8;

  f32x4 acc[4][4] = {};

  for (int k0 = 0; k0 < HH; k0 += PBK) {
    // ---- W: 4 rounds of global_load_lds (16 B/lane, linear LDS) ----
#pragma unroll
    for (int p = 0; p < 4; ++p) {
      const int u = p * 256 + t;            // 0..1023
      const int r = u >> 3, c8 = u & 7;
      const ushort* gsrc = Wb + (size_t)(n0 + r) * HH + k0 + c8 * 8;
      __builtin_amdgcn_global_load_lds(
          (const __attribute__((address_space(1))) uint*)gsrc,
          (__attribute__((address_space(3))) uint*)(Ws + p * 2048 + w * 512),
          16, 0, 0);
    }
    // ---- A: reg-stage fp32 -> bf16 (compiler cvt) ----
#pragma unroll
    for (int p = 0; p < 4; ++p) {
      const int u = p * 256 + t;
      const int r = u >> 3, c8 = u & 7;
      const float* g = A + (size_t)(m0 + r) * HH + k0 + c8 * 8;
      float4 x = ((const float4*)g)[0], y = ((const float4*)g)[1];
      union { ushort s[8]; uint4 v; } pk;
      pk.s[0]=cvt1(x.x); pk.s[1]=cvt1(x.y); pk.s[2]=cvt1(x.z); pk.s[3]=cvt1(x.w);
      pk.s[4]=cvt1(y.x); pk.s[5]=cvt1(y.y); pk.s[6]=cvt1(y.z); pk.s[7]=cvt1(y.w);
      *(uint4*)&As[u * 8] = pk.v;
    }
    __syncthreads();

#pragma unroll
    for (int kk = 0; kk < PBK; kk += 32) {
      bf16x8 af[4], bf[4];
#pragma unroll
      for (int m = 0; m < 4; ++m)
        af[m] = *(const bf16x8*)&As[(wr + m * 16 + lr) * PBK + kk + lk8];
#pragma unroll
      for (int n = 0; n < 4; ++n)
        bf[n] = *(const bf16x8*)&Ws[(wc + n * 16 + lr) * PBK + kk + lk8];
#pragma unroll
      for (int m = 0; m < 4; ++m)
#pragma unroll
        for (int n = 0; n < 4; ++n)
          acc[m][n] = __builtin_amdgcn_mfma_f32_16x16x32_bf16(af[m], bf[n], acc[m][n], 0, 0, 0);
    }
    __syncthreads();
  }

  // ---- epilogue: D row=(l>>4)*4+q, col=l&15 (round-3/4 verified) ----
#pragma unroll
  for (int n = 0; n < 4; ++n) {
    const int col = n0 + wc + n * 16 + lr;
    const float bc = bias[col];
#pragma unroll
    for (int m = 0; m < 4; ++m) {
      const int rbase = m0 + wr + m * 16 + (l >> 4) * 4;
#pragma unroll
      for (int q = 0; q < 4; ++q)
        C[(size_t)(rbase + q) * HH + col] = f2bf(acc[m][n][q] + bc);
    }
  }
}

// ---------------- MFMA windowed attention + softmax + gather --------------
// One wave per (16-row tile, head). Window-union span <= 48 K-rows.
// S[16][48] = 3 accs of 16x16 via 6 mfma_f32_16x16x32_bf16, fragments
// loaded DIRECTLY from global (no LDS). In-register softmax via shfl_xor
// across the 16 lanes holding one row. Masked-but-gathered cols store 0.
__global__ __launch_bounds__(256) void attn_mfma(
    const ushort* __restrict__ Q, const ushort* __restrict__ Kp,
    float* __restrict__ out)
{
  const int gw = blockIdx.x * 4 + (threadIdx.x >> 6);   // 0..4095
  const int h = gw & 7;
  const int tile = gw >> 3;          // 0..511
  const int b = tile >> 7;           // 128 row-tiles per batch
  const int i0 = (tile & 127) * 16;
  const int l = threadIdx.x & 63;
  const int lo = l & 15;             // fragment row/col lane index
  const int hi = l >> 4;             // k-slice / acc row-group

  int jb = i0 - WIN;                 // jb = start(i0) = clip(i0-16,0,T-33)
  if (jb < 0) jb = 0;
  if (jb > TT - NC) jb = TT - NC;

  // ---- A fragment: Q rows i0+lo, k = h*64 + ks*32 + hi*8 ----
  const size_t qbase = ((size_t)(b * TT + i0 + lo)) * HH + h * DK + hi * 8;
  bf16x8 aq0 = *(const bf16x8*)(Q + qbase);
  bf16x8 aq1 = *(const bf16x8*)(Q + qbase + 32);

  // ---- B fragments: K rows jb+16a+lo (clamped), + 6 MFMAs ----
  f32x4 acc[3] = {};
#pragma unroll
  for (int a = 0; a < 3; ++a) {
    int j = jb + a * 16 + lo;
    if (j > TT - 1) j = TT - 1;      // clamped loads get masked below
    const size_t kbase = ((size_t)(b * TT + j)) * HH + h * DK + hi * 8;
    bf16x8 bk0 = *(const bf16x8*)(Kp + kbase);
    bf16x8 bk1 = *(const bf16x8*)(Kp + kbase + 32);
    acc[a] = __builtin_amdgcn_mfma_f32_16x16x32_bf16(aq0, bk0, acc[a], 0, 0, 0);
    acc[a] = __builtin_amdgcn_mfma_f32_16x16x32_bf16(aq1, bk1, acc[a], 0, 0, 0);
  }

  // ---- softmax per row (row = i0 + hi*4 + q, cols j = jb + 16a + lo) ----
  float e[3][4];
  float inv[4];
#pragma unroll
  for (int q = 0; q < 4; ++q) {
    const int i = i0 + hi * 4 + q;
    float s0, s1, s2;
    {
      const int j0 = jb + lo, j1 = j0 + 16, j2 = j0 + 32;
      s0 = (j0 >= i - WIN && j0 <= i + WIN && j0 < TT) ? acc[0][q] * 0.125f : -INFINITY;
      s1 = (j1 >= i - WIN && j1 <= i + WIN && j1 < TT) ? acc[1][q] * 0.125f : -INFINITY;
      s2 = (j2 >= i - WIN && j2 <= i + WIN && j2 < TT) ? acc[2][q] * 0.125f : -INFINITY;
    }
    float m = fmaxf(fmaxf(s0, s1), s2);
#pragma unroll
    for (int off = 8; off; off >>= 1) m = fmaxf(m, __shfl_xor(m, off));
    const float e0 = __expf(s0 - m);   // expf(-inf)=0 for masked
    const float e1 = __expf(s1 - m);
    const float e2 = __expf(s2 - m);
    e[0][q] = e0; e[1][q] = e1; e[2][q] = e2;
    float sum = e0 + e1 + e2;
#pragma unroll
    for (int off = 8; off; off >>= 1) sum += __shfl_xor(sum, off);
    inv[q] = 1.0f / sum;
  }

  // ---- scatter to gathered layout: c = j - start(i), 0 <= c < 33 ----
  const size_t obase = ((size_t)(b * NH + h)) * TT * NC;
#pragma unroll
  for (int q = 0; q < 4; ++q) {
    const int i = i0 + hi * 4 + q;
    int st = i - WIN;
    if (st < 0) st = 0;
    if (st > TT - NC) st = TT - NC;
#pragma unroll
    for (int a = 0; a < 3; ++a) {
      const int c = jb + a * 16 + lo - st;
      if (c >= 0 && c < NC)
        out[obase + (size_t)i * NC + c] = e[a][q] * inv[q];
    }
  }
}

extern "C" void kernel_launch(void* const* d_in, const int* in_sizes, int n_in,
                              void* d_out, int out_size, void* d_ws, size_t ws_size,
                              hipStream_t stream)
{
  const float* query = (const float*)d_in[0];
  const float* key   = (const float*)d_in[1];
  const float* Wq    = (const float*)d_in[2];
  const float* bq    = (const float*)d_in[3];
  const float* Wk    = (const float*)d_in[4];
  const float* bk    = (const float*)d_in[5];
  float* out = (float*)d_out;

  const int B = 4, M = B * TT;      // 8192 rows
  ushort* Wqb = (ushort*)d_ws;                  // 512x512 bf16
  ushort* Wkb = Wqb + (size_t)HH * HH;
  ushort* Qp  = Wkb + (size_t)HH * HH;          // [M, 512] bf16
  ushort* Kp  = Qp + (size_t)M * HH;

  cvt_w<<<256, 256, 0, stream>>>(Wq, Wk, Wqb, Wkb);
  proj_mfma<<<dim3(M / PBM, HH / PBN, 2), 256, 0, stream>>>(
      query, key, Wqb, Wkb, bq, bk, Qp, Kp);
  attn_mfma<<<dim3((M / 16) * NH / 4), 256, 0, stream>>>(Qp, Kp, out);
}